// Round 7
// baseline (477.747 us; speedup 1.0000x reference)
//
#include <hip/hip_runtime.h>

#define B_  2
#define N_  100000
#define NE_ 800000
#define F_  2
#define D_  128
#define TD_ 11
#define CD_ 32
#define SD_ 10

#define NODE_BX   782                      // ceil(N/128)
#define NODE_NB   (NODE_BX * F_ * B_)      // 3128
#define EDGE_BX   6250                     // NE/128
#define EDGE_NB   (EDGE_BX * B_)           // 12500
#define GROUPS    3125                     // groups of 5 (1 node + 4 edge)
#define TOTAL_NB  (NODE_NB + EDGE_NB)      // 15628

// workspace byte offsets
#define WS_GB      0        // float[512]  gamma/beta
#define WS_FLAG    2048     // float       edges-are-int64 flag
#define WS_W1PACK  2112     // bf16[3][128][8]   (node f0, node f1, edge folded)
#define WS_W2FRAG  8448     // bf16[3][2048][8]  (A-frag layout, node f0/f1, edge)

typedef short s16x8 __attribute__((ext_vector_type(8)));
typedef float f32x4 __attribute__((ext_vector_type(4)));

static __device__ __forceinline__ unsigned short f2bf(float f) {
    unsigned u = __builtin_bit_cast(unsigned, f);
    u += 0x7FFFu + ((u >> 16) & 1u);   // RNE
    return (unsigned short)(u >> 16);
}
static __device__ __forceinline__ float bits2f(unsigned short s) {
    unsigned u = ((unsigned)s) << 16;
    return __builtin_bit_cast(float, u);
}
static __device__ __forceinline__ float silu_f(float x) { return x / (1.0f + __expf(-x)); }

// ---------------------------------------------------------------------------
// Prep kernel (grid=6, 256 thr): FiLM (bx 0/1), w2 A-frag packs (bx 2/3/4),
// w1 packs + edge dtype probe (bx 5).
// ---------------------------------------------------------------------------
__global__ void prep_kernel(
    const float* __restrict__ time_i, const float* __restrict__ cond,
    const float* __restrict__ spat,
    const float* tw1, const float* tb1, const float* tw2, const float* tb2,
    const float* cw1, const float* cb1, const float* cw2, const float* cb2,
    const float* sw1, const float* sb1, const float* sw2, const float* sb2,
    const float* fuw1, const float* fub1, const float* fuw2, const float* fub2,
    const float* __restrict__ fw1, const float* __restrict__ fb1,
    const float* __restrict__ fw2,
    const float* __restrict__ ew1, const float* __restrict__ eb1,
    const float* __restrict__ ew2,
    const int* __restrict__ edges,
    char* __restrict__ ws)
{
    const int bx = blockIdx.x, t = threadIdx.x;

    if (bx < 2) {
        // ---- FiLM for batch b = bx ----
        const int b = bx, d = t;
        __shared__ float h[3 * D_];
        __shared__ float hid[D_];

        const float* X [3] = { cond + b * CD_, time_i + b * TD_, spat + b * SD_ };
        const float* W1[3] = { cw1, tw1, sw1 };
        const float* B1[3] = { cb1, tb1, sb1 };
        const float* W2[3] = { cw2, tw2, sw2 };
        const float* B2[3] = { cb2, tb2, sb2 };
        const int    K [3] = { CD_, TD_, SD_ };

        for (int m = 0; m < 3; ++m) {
            float a = 0.f;
            if (d < D_) {
                a = B1[m][d];
                for (int k = 0; k < K[m]; ++k) a += X[m][k] * W1[m][k * D_ + d];
            }
            __syncthreads();
            if (d < D_) hid[d] = silu_f(a);
            __syncthreads();
            if (d < D_) {
                float o = B2[m][d];
                for (int k = 0; k < D_; ++k) o += hid[k] * W2[m][k * D_ + d];
                h[m * D_ + d] = o;
            }
        }
        __syncthreads();
        float pre2 = 0.f;
        if (d < D_) {
            pre2 = fub1[d];
            for (int k = 0; k < 3 * D_; ++k) pre2 += h[k] * fuw1[k * D_ + d];
        }
        __syncthreads();
        if (d < D_) hid[d] = silu_f(pre2);
        __syncthreads();
        if (d < D_) {
            float g = fub2[d], be = fub2[D_ + d];
            for (int k = 0; k < D_; ++k) {
                float hv = hid[k];
                g  += hv * fuw2[k * 2 * D_ + d];
                be += hv * fuw2[k * 2 * D_ + D_ + d];
            }
            float* gb = (float*)ws;
            gb[(b * 2 + 0) * D_ + d] = g;
            gb[(b * 2 + 1) * D_ + d] = be;
        }
    } else if (bx < 5) {
        // ---- w2 A-frag pack: which 0/1 = node fields, 2 = edge ----
        const int which = bx - 2;
        const float* src = (which < 2) ? (fw2 + which * D_ * D_) : ew2;
        unsigned short* dst = (unsigned short*)(ws + WS_W2FRAG) + (long)which * 2048 * 8;
        for (int e = t; e < 2048; e += 256) {
            const int lanee = e & 63, kb = (e >> 6) & 3, nt = e >> 8;
            const int out = nt * 16 + (lanee & 15);
            const int k0  = kb * 32 + (lanee >> 4) * 8;
            s16x8 v;
            #pragma unroll
            for (int i = 0; i < 8; ++i)
                v[i] = (short)f2bf(src[(k0 + i) * D_ + out]);
            *(s16x8*)(dst + e * 8) = v;
        }
    } else {
        // ---- w1 packs + edge dtype probe ----
        unsigned short* w1p = (unsigned short*)(ws + WS_W1PACK);
        if (t == 0) {   // int64 edges => odd int32 words of the first 64 all 0
            int nz = 0;
            for (int j = 0; j < 64; ++j) nz |= edges[2 * j + 1];
            ((float*)(ws + WS_FLAG))[0] = (nz == 0) ? 1.0f : 0.0f;
        }
        {
            const int f = t >> 7, e = t & 127;   // node fields
            s16x8 v;
            #pragma unroll
            for (int k = 0; k < 4; ++k) v[k] = (short)f2bf(fw1[(f * 4 + k) * D_ + e]);
            v[4] = (short)f2bf(fb1[f * D_ + e]);
            v[5] = 0; v[6] = 0; v[7] = 0;
            *(s16x8*)(w1p + (f * 128 + e) * 8) = v;
        }
        if (t < 128) {   // edge, folded: [d,-d,norm] -> 4 effective weights
            const int e = t;
            s16x8 v;
            v[0] = (short)f2bf(ew1[0 * D_ + e] - ew1[3 * D_ + e]);
            v[1] = (short)f2bf(ew1[1 * D_ + e] - ew1[4 * D_ + e]);
            v[2] = (short)f2bf(ew1[2 * D_ + e] - ew1[5 * D_ + e]);
            v[3] = (short)f2bf(ew1[6 * D_ + e]);
            v[4] = (short)f2bf(eb1[e]);
            v[5] = 0; v[6] = 0; v[7] = 0;
            *(s16x8*)(w1p + (2 * 128 + e) * 8) = v;
        }
    }
}

// ---------------------------------------------------------------------------
// Shared MLP tail: hidden (f32 VALU -> bf16) + MFMA layer2 (A=w2frag, B=hid)
// + vectorized epilogue. No LDS, no barriers.
// ---------------------------------------------------------------------------
template<bool FILM>
static __device__ __forceinline__ void mlp_tail(
    int lane, int wv, int kg, int lr,
    const float xa[4], const float xb[4],
    const unsigned short* __restrict__ w1p,   // [128][8] bf16
    const unsigned short* __restrict__ w2f,   // [8][4][64][8] bf16 A-frags
    const float* __restrict__ bias,           // [128] f32
    const float* __restrict__ gamma,          // [128] f32 (FILM only)
    const float* __restrict__ beta,
    float* __restrict__ base,                 // output row 0 of this tile
    long stride, int rowsValid)
{
    f32x4 acc[2][8];
    #pragma unroll
    for (int mt = 0; mt < 2; ++mt)
        #pragma unroll
        for (int nt = 0; nt < 8; ++nt) acc[mt][nt] = (f32x4){0.f, 0.f, 0.f, 0.f};

    #pragma unroll
    for (int kb = 0; kb < 4; ++kb) {
        const int e0 = kb * 32 + kg * 8;
        s16x8 ua, ub;
        #pragma unroll
        for (int i = 0; i < 8; ++i) {
            s16x8 w8 = *(const s16x8*)(w1p + (e0 + i) * 8);
            const float w0 = bits2f((unsigned short)w8[0]);
            const float w1 = bits2f((unsigned short)w8[1]);
            const float w2 = bits2f((unsigned short)w8[2]);
            const float w3 = bits2f((unsigned short)w8[3]);
            const float bb = bits2f((unsigned short)w8[4]);
            ua[i] = (short)f2bf(silu_f(xa[0]*w0 + xa[1]*w1 + xa[2]*w2 + xa[3]*w3 + bb));
            ub[i] = (short)f2bf(silu_f(xb[0]*w0 + xb[1]*w1 + xb[2]*w2 + xb[3]*w3 + bb));
        }
        #pragma unroll
        for (int nt = 0; nt < 8; ++nt) {
            s16x8 afr = *(const s16x8*)(w2f + ((nt * 4 + kb) * 64 + lane) * 8);
            acc[0][nt] = __builtin_amdgcn_mfma_f32_16x16x32_bf16(afr, ua, acc[0][nt], 0, 0, 0);
            acc[1][nt] = __builtin_amdgcn_mfma_f32_16x16x32_bf16(afr, ub, acc[1][nt], 0, 0, 0);
        }
    }

    // Epilogue: lane holds out-dims [nt*16+kg*4 .. +3] for node/edge (wv*32+mt*16+lr)
    #pragma unroll
    for (int nt = 0; nt < 8; ++nt) {
        const int d0 = nt * 16 + kg * 4;
        const f32x4 bs = *(const f32x4*)(bias + d0);
        f32x4 g, be;
        if (FILM) { g = *(const f32x4*)(gamma + d0); be = *(const f32x4*)(beta + d0); }
        #pragma unroll
        for (int mt = 0; mt < 2; ++mt) {
            const int m = wv * 32 + mt * 16 + lr;
            if (m < rowsValid) {
                f32x4 v;
                #pragma unroll
                for (int r = 0; r < 4; ++r)
                    v[r] = FILM ? (acc[mt][nt][r] + bs[r]) * g[r] + be[r]
                                : acc[mt][nt][r] + bs[r];
                __builtin_nontemporal_store(v, (f32x4*)(base + (long)m * stride + d0));
            }
        }
    }
}

// ---------------------------------------------------------------------------
// Fused kernel: interleaved node/edge roles (1:4). No LDS, no barriers.
// ---------------------------------------------------------------------------
__global__ __launch_bounds__(256, 3) void fused_kernel(
    const float* __restrict__ pos, const float* __restrict__ state,
    const int* __restrict__ edges,
    const float* __restrict__ fb2, const float* __restrict__ eb2,
    const char* __restrict__ ws,
    float* __restrict__ V, float* __restrict__ E)
{
    const int bx = blockIdx.x, t = threadIdx.x;
    const int lane = t & 63, wv = t >> 6;
    const int kg = lane >> 4, lr = lane & 15;

    const float* gbAll = (const float*)ws;
    const unsigned short* w1all = (const unsigned short*)(ws + WS_W1PACK);
    const unsigned short* w2all = (const unsigned short*)(ws + WS_W2FRAG);

    bool isNode; int sub;
    if (bx >= 5 * GROUPS) { isNode = true; sub = GROUPS + (bx - 5 * GROUPS); }
    else {
        int g = bx / 5, s = bx - 5 * g;
        if (s == 0) { isNode = true;  sub = g; }
        else        { isNode = false; sub = g * 4 + (s - 1); }
    }

    float xa[4], xb[4];

    if (isNode) {
        const int n0 = (sub % NODE_BX) * 128;
        const int f  = (sub / NODE_BX) & 1;
        const int b  = sub / (NODE_BX * F_);

        int na = n0 + wv * 32 + lr;      if (na >= N_) na = N_ - 1;
        int nb = n0 + wv * 32 + lr + 16; if (nb >= N_) nb = N_ - 1;
        long pa = ((long)b * N_ + na) * 3, pb = ((long)b * N_ + nb) * 3;
        xa[0] = pos[pa]; xa[1] = pos[pa + 1]; xa[2] = pos[pa + 2];
        xb[0] = pos[pb]; xb[1] = pos[pb + 1]; xb[2] = pos[pb + 2];
        xa[3] = state[((long)b * N_ + na) * F_ + f];
        xb[3] = state[((long)b * N_ + nb) * F_ + f];

        mlp_tail<true>(lane, wv, kg, lr, xa, xb,
                       w1all + f * 128 * 8,
                       w2all + (long)f * 2048 * 8,
                       fb2 + f * D_,
                       gbAll + b * 2 * D_, gbAll + b * 2 * D_ + D_,
                       V + (((long)b * N_ + n0) * F_ + f) * D_,
                       (long)F_ * D_, N_ - n0);
    } else {
        const int e0blk = (sub % EDGE_BX) * 128;
        const int b     = sub / EDGE_BX;

        const bool x64 = ((const float*)(ws + WS_FLAG))[0] > 0.5f;
        const long ea = (long)b * NE_ + e0blk + wv * 32 + lr;
        const long eb = ea + 16;
        int sa, ra, sb, rb;
        if (x64) {
            sa = edges[ea * 4]; ra = edges[ea * 4 + 2];
            sb = edges[eb * 4]; rb = edges[eb * 4 + 2];
        } else {
            int2 va = *(const int2*)(edges + ea * 2); sa = va.x; ra = va.y;
            int2 vb = *(const int2*)(edges + eb * 2); sb = vb.x; rb = vb.y;
        }
        const float* pp = pos + (long)b * N_ * 3;
        {
            long so = (long)sa * 3, ro = (long)ra * 3;
            xa[0] = pp[ro]     - pp[so];
            xa[1] = pp[ro + 1] - pp[so + 1];
            xa[2] = pp[ro + 2] - pp[so + 2];
            xa[3] = sqrtf(xa[0]*xa[0] + xa[1]*xa[1] + xa[2]*xa[2] + 1e-8f);
        }
        {
            long so = (long)sb * 3, ro = (long)rb * 3;
            xb[0] = pp[ro]     - pp[so];
            xb[1] = pp[ro + 1] - pp[so + 1];
            xb[2] = pp[ro + 2] - pp[so + 2];
            xb[3] = sqrtf(xb[0]*xb[0] + xb[1]*xb[1] + xb[2]*xb[2] + 1e-8f);
        }

        mlp_tail<false>(lane, wv, kg, lr, xa, xb,
                        w1all + 2 * 128 * 8,
                        w2all + (long)2 * 2048 * 8,
                        eb2, nullptr, nullptr,
                        E + ((long)b * NE_ + e0blk) * D_,
                        (long)D_, 128);
    }
}

// ---------------------------------------------------------------------------
extern "C" void kernel_launch(void* const* d_in, const int* in_sizes, int n_in,
                              void* d_out, int out_size, void* d_ws, size_t ws_size,
                              hipStream_t stream)
{
    (void)in_sizes; (void)n_in; (void)out_size; (void)ws_size;

    const float* node_pos  = (const float*)d_in[0];
    const float* state_in  = (const float*)d_in[1];
    const float* time_i    = (const float*)d_in[2];
    const float* conditions= (const float*)d_in[3];
    const float* spatial   = (const float*)d_in[4];
    const int*   edges     = (const int*)d_in[5];
    const float* fields_w1 = (const float*)d_in[6];
    const float* fields_b1 = (const float*)d_in[7];
    const float* fields_w2 = (const float*)d_in[8];
    const float* fields_b2 = (const float*)d_in[9];
    const float* tw1 = (const float*)d_in[10];
    const float* tb1 = (const float*)d_in[11];
    const float* tw2 = (const float*)d_in[12];
    const float* tb2 = (const float*)d_in[13];
    const float* cw1 = (const float*)d_in[14];
    const float* cb1 = (const float*)d_in[15];
    const float* cw2 = (const float*)d_in[16];
    const float* cb2 = (const float*)d_in[17];
    const float* sw1 = (const float*)d_in[18];
    const float* sb1 = (const float*)d_in[19];
    const float* sw2 = (const float*)d_in[20];
    const float* sb2 = (const float*)d_in[21];
    const float* fu_w1 = (const float*)d_in[22];
    const float* fu_b1 = (const float*)d_in[23];
    const float* fu_w2 = (const float*)d_in[24];
    const float* fu_b2 = (const float*)d_in[25];
    const float* fe_w1 = (const float*)d_in[26];
    const float* fe_b1 = (const float*)d_in[27];
    const float* fe_w2 = (const float*)d_in[28];
    const float* fe_b2 = (const float*)d_in[29];

    char*  ws = (char*)d_ws;
    float* V  = (float*)d_out;                // [B][N][F][D] f32
    float* E  = V + (long)B_ * N_ * F_ * D_;  // [B][NE][D] f32

    prep_kernel<<<dim3(6), dim3(256), 0, stream>>>(
        time_i, conditions, spatial,
        tw1, tb1, tw2, tb2, cw1, cb1, cw2, cb2, sw1, sb1, sw2, sb2,
        fu_w1, fu_b1, fu_w2, fu_b2,
        fields_w1, fields_b1, fields_w2,
        fe_w1, fe_b1, fe_w2,
        edges, ws);

    fused_kernel<<<dim3(TOTAL_NB), dim3(256), 0, stream>>>(
        node_pos, state_in, edges, fields_b2, fe_b2, ws, V, E);
}

// Round 8
// 285.569 us; speedup vs baseline: 1.6730x; 1.6730x over previous
//
#include <hip/hip_runtime.h>

#define B_  2
#define N_  100000
#define NE_ 800000
#define F_  2
#define D_  128
#define TD_ 11
#define CD_ 32
#define SD_ 10

#define NODE_BX   782                      // ceil(N/128)
#define NODE_NB   (NODE_BX * F_ * B_)      // 3128
#define EDGE_BX   6250                     // NE/128
#define EDGE_NB   (EDGE_BX * B_)           // 12500
#define GROUPS    3125                     // groups of 5 (1 node + 4 edge)
#define TOTAL_NB  (NODE_NB + EDGE_NB)      // 15628

// workspace byte offsets
#define WS_GB      0        // float[512]  gamma/beta
#define WS_FLAG    2048     // float       edges-are-int64 flag
#define WS_W1PACK  2112     // bf16[3][128][8]   (node f0, node f1, edge folded)
#define WS_W2FRAG  8448     // bf16[3][2048][8]  (frag layout, node f0/f1, edge)

typedef short s16x8 __attribute__((ext_vector_type(8)));
typedef float f32x4 __attribute__((ext_vector_type(4)));

static __device__ __forceinline__ unsigned short f2bf(float f) {
    unsigned u = __builtin_bit_cast(unsigned, f);
    u += 0x7FFFu + ((u >> 16) & 1u);   // RNE
    return (unsigned short)(u >> 16);
}
static __device__ __forceinline__ float bits2f(unsigned short s) {
    unsigned u = ((unsigned)s) << 16;
    return __builtin_bit_cast(float, u);
}
static __device__ __forceinline__ float silu_f(float x) { return x / (1.0f + __expf(-x)); }

// ---------------------------------------------------------------------------
// Prep kernel (grid=6, 256 thr): FiLM (bx 0/1), w2 frag packs (bx 2/3/4),
// w1 packs + edge dtype probe (bx 5).  (unchanged from round 7 — validated)
// ---------------------------------------------------------------------------
__global__ void prep_kernel(
    const float* __restrict__ time_i, const float* __restrict__ cond,
    const float* __restrict__ spat,
    const float* tw1, const float* tb1, const float* tw2, const float* tb2,
    const float* cw1, const float* cb1, const float* cw2, const float* cb2,
    const float* sw1, const float* sb1, const float* sw2, const float* sb2,
    const float* fuw1, const float* fub1, const float* fuw2, const float* fub2,
    const float* __restrict__ fw1, const float* __restrict__ fb1,
    const float* __restrict__ fw2,
    const float* __restrict__ ew1, const float* __restrict__ eb1,
    const float* __restrict__ ew2,
    const int* __restrict__ edges,
    char* __restrict__ ws)
{
    const int bx = blockIdx.x, t = threadIdx.x;

    if (bx < 2) {
        const int b = bx, d = t;
        __shared__ float h[3 * D_];
        __shared__ float hid[D_];

        const float* X [3] = { cond + b * CD_, time_i + b * TD_, spat + b * SD_ };
        const float* W1[3] = { cw1, tw1, sw1 };
        const float* B1[3] = { cb1, tb1, sb1 };
        const float* W2[3] = { cw2, tw2, sw2 };
        const float* B2[3] = { cb2, tb2, sb2 };
        const int    K [3] = { CD_, TD_, SD_ };

        for (int m = 0; m < 3; ++m) {
            float a = 0.f;
            if (d < D_) {
                a = B1[m][d];
                for (int k = 0; k < K[m]; ++k) a += X[m][k] * W1[m][k * D_ + d];
            }
            __syncthreads();
            if (d < D_) hid[d] = silu_f(a);
            __syncthreads();
            if (d < D_) {
                float o = B2[m][d];
                for (int k = 0; k < D_; ++k) o += hid[k] * W2[m][k * D_ + d];
                h[m * D_ + d] = o;
            }
        }
        __syncthreads();
        float pre2 = 0.f;
        if (d < D_) {
            pre2 = fub1[d];
            for (int k = 0; k < 3 * D_; ++k) pre2 += h[k] * fuw1[k * D_ + d];
        }
        __syncthreads();
        if (d < D_) hid[d] = silu_f(pre2);
        __syncthreads();
        if (d < D_) {
            float g = fub2[d], be = fub2[D_ + d];
            for (int k = 0; k < D_; ++k) {
                float hv = hid[k];
                g  += hv * fuw2[k * 2 * D_ + d];
                be += hv * fuw2[k * 2 * D_ + D_ + d];
            }
            float* gb = (float*)ws;
            gb[(b * 2 + 0) * D_ + d] = g;
            gb[(b * 2 + 1) * D_ + d] = be;
        }
    } else if (bx < 5) {
        const int which = bx - 2;
        const float* src = (which < 2) ? (fw2 + which * D_ * D_) : ew2;
        unsigned short* dst = (unsigned short*)(ws + WS_W2FRAG) + (long)which * 2048 * 8;
        for (int e = t; e < 2048; e += 256) {
            const int lanee = e & 63, kb = (e >> 6) & 3, nt = e >> 8;
            const int out = nt * 16 + (lanee & 15);
            const int k0  = kb * 32 + (lanee >> 4) * 8;
            s16x8 v;
            #pragma unroll
            for (int i = 0; i < 8; ++i)
                v[i] = (short)f2bf(src[(k0 + i) * D_ + out]);
            *(s16x8*)(dst + e * 8) = v;
        }
    } else {
        unsigned short* w1p = (unsigned short*)(ws + WS_W1PACK);
        if (t == 0) {
            int nz = 0;
            for (int j = 0; j < 64; ++j) nz |= edges[2 * j + 1];
            ((float*)(ws + WS_FLAG))[0] = (nz == 0) ? 1.0f : 0.0f;
        }
        {
            const int f = t >> 7, e = t & 127;
            s16x8 v;
            #pragma unroll
            for (int k = 0; k < 4; ++k) v[k] = (short)f2bf(fw1[(f * 4 + k) * D_ + e]);
            v[4] = (short)f2bf(fb1[f * D_ + e]);
            v[5] = 0; v[6] = 0; v[7] = 0;
            *(s16x8*)(w1p + (f * 128 + e) * 8) = v;
        }
        if (t < 128) {
            const int e = t;
            s16x8 v;
            v[0] = (short)f2bf(ew1[0 * D_ + e] - ew1[3 * D_ + e]);
            v[1] = (short)f2bf(ew1[1 * D_ + e] - ew1[4 * D_ + e]);
            v[2] = (short)f2bf(ew1[2 * D_ + e] - ew1[5 * D_ + e]);
            v[3] = (short)f2bf(ew1[6 * D_ + e]);
            v[4] = (short)f2bf(eb1[e]);
            v[5] = 0; v[6] = 0; v[7] = 0;
            *(s16x8*)(w1p + (2 * 128 + e) * 8) = v;
        }
    }
}

// ---------------------------------------------------------------------------
// Fused kernel: interleaved node/edge roles (1:4).
//  - w1/w2-frag staged ws->LDS once per block (vector, conflict-free)
//  - MFMA reads operands from LDS
//  - epilogue bounces through LDS f32 tile -> full-128B-line NT stores
// ---------------------------------------------------------------------------
__global__ __launch_bounds__(256, 4) void fused_kernel(
    const float* __restrict__ pos, const float* __restrict__ state,
    const int* __restrict__ edges,
    const float* __restrict__ fb2, const float* __restrict__ eb2,
    const char* __restrict__ ws,
    float* __restrict__ V, float* __restrict__ E)
{
    __shared__ __align__(16) char smem[36864];
    unsigned short* w2lds = (unsigned short*)smem;           // 32KB (dead after MFMA)
    float*          outF  = (float*)smem;                    // [128][68] f32 (34816B)
    unsigned short* w1lds = (unsigned short*)(smem + 34816); // 2KB

    const int bx = blockIdx.x, t = threadIdx.x;
    const int lane = t & 63, wv = t >> 6;
    const int kg = lane >> 4, lr = lane & 15;

    const float* gbAll = (const float*)ws;
    const unsigned short* w1all = (const unsigned short*)(ws + WS_W1PACK);
    const unsigned short* w2all = (const unsigned short*)(ws + WS_W2FRAG);

    bool isNode; int sub;
    if (bx >= 5 * GROUPS) { isNode = true; sub = GROUPS + (bx - 5 * GROUPS); }
    else {
        int g = bx / 5, s = bx - 5 * g;
        if (s == 0) { isNode = true;  sub = g; }
        else        { isNode = false; sub = g * 4 + (s - 1); }
    }

    // ---- role decode + input gather (issue global loads early) ----
    float xa[4], xb[4];
    int n0 = 0, f = 0, b, e0blk = 0;
    if (isNode) {
        n0 = (sub % NODE_BX) * 128;
        f  = (sub / NODE_BX) & 1;
        b  = sub / (NODE_BX * F_);
        int na = n0 + wv * 32 + lr;      if (na >= N_) na = N_ - 1;
        int nb = n0 + wv * 32 + lr + 16; if (nb >= N_) nb = N_ - 1;
        long pa = ((long)b * N_ + na) * 3, pb = ((long)b * N_ + nb) * 3;
        xa[0] = pos[pa]; xa[1] = pos[pa + 1]; xa[2] = pos[pa + 2];
        xb[0] = pos[pb]; xb[1] = pos[pb + 1]; xb[2] = pos[pb + 2];
        xa[3] = state[((long)b * N_ + na) * F_ + f];
        xb[3] = state[((long)b * N_ + nb) * F_ + f];
    } else {
        e0blk = (sub % EDGE_BX) * 128;
        b     = sub / EDGE_BX;
        const bool x64 = ((const float*)(ws + WS_FLAG))[0] > 0.5f;
        const long ea = (long)b * NE_ + e0blk + wv * 32 + lr;
        const long eb = ea + 16;
        int sa, ra, sb, rb;
        if (x64) {
            sa = edges[ea * 4]; ra = edges[ea * 4 + 2];
            sb = edges[eb * 4]; rb = edges[eb * 4 + 2];
        } else {
            int2 va = *(const int2*)(edges + ea * 2); sa = va.x; ra = va.y;
            int2 vb = *(const int2*)(edges + eb * 2); sb = vb.x; rb = vb.y;
        }
        const float* pp = pos + (long)b * N_ * 3;
        {
            long so = (long)sa * 3, ro = (long)ra * 3;
            xa[0] = pp[ro]     - pp[so];
            xa[1] = pp[ro + 1] - pp[so + 1];
            xa[2] = pp[ro + 2] - pp[so + 2];
            xa[3] = sqrtf(xa[0]*xa[0] + xa[1]*xa[1] + xa[2]*xa[2] + 1e-8f);
        }
        {
            long so = (long)sb * 3, ro = (long)rb * 3;
            xb[0] = pp[ro]     - pp[so];
            xb[1] = pp[ro + 1] - pp[so + 1];
            xb[2] = pp[ro + 2] - pp[so + 2];
            xb[3] = sqrtf(xb[0]*xb[0] + xb[1]*xb[1] + xb[2]*xb[2] + 1e-8f);
        }
    }

    // ---- stage w2 frags (32KB) + w1 pack (2KB) into LDS ----
    {
        const int which = isNode ? f : 2;
        const char* src = (const char*)(w2all + (long)which * 2048 * 8);
        #pragma unroll
        for (int j = 0; j < 8; ++j) {
            f32x4 v = *(const f32x4*)(src + (j * 256 + t) * 16);
            *(f32x4*)((char*)w2lds + (j * 256 + t) * 16) = v;
        }
        if (t < 128) {
            f32x4 v = *(const f32x4*)((const char*)(w1all + which * 128 * 8) + t * 16);
            *(f32x4*)((char*)w1lds + t * 16) = v;
        }
    }
    __syncthreads();

    // ---- hidden layer (f32 VALU -> bf16) + MFMA layer2 ----
    f32x4 acc[2][8];
    #pragma unroll
    for (int mt = 0; mt < 2; ++mt)
        #pragma unroll
        for (int nt = 0; nt < 8; ++nt) acc[mt][nt] = (f32x4){0.f, 0.f, 0.f, 0.f};

    #pragma unroll
    for (int kb = 0; kb < 4; ++kb) {
        const int e0 = kb * 32 + kg * 8;
        s16x8 ua, ub;
        #pragma unroll
        for (int i = 0; i < 8; ++i) {
            s16x8 w8 = *(const s16x8*)(w1lds + (e0 + i) * 8);
            const float w0 = bits2f((unsigned short)w8[0]);
            const float w1 = bits2f((unsigned short)w8[1]);
            const float w2 = bits2f((unsigned short)w8[2]);
            const float w3 = bits2f((unsigned short)w8[3]);
            const float bb = bits2f((unsigned short)w8[4]);
            ua[i] = (short)f2bf(silu_f(xa[0]*w0 + xa[1]*w1 + xa[2]*w2 + xa[3]*w3 + bb));
            ub[i] = (short)f2bf(silu_f(xb[0]*w0 + xb[1]*w1 + xb[2]*w2 + xb[3]*w3 + bb));
        }
        #pragma unroll
        for (int nt = 0; nt < 8; ++nt) {
            s16x8 afr = *(const s16x8*)(w2lds + ((nt * 4 + kb) * 64 + lane) * 8);
            acc[0][nt] = __builtin_amdgcn_mfma_f32_16x16x32_bf16(afr, ua, acc[0][nt], 0, 0, 0);
            acc[1][nt] = __builtin_amdgcn_mfma_f32_16x16x32_bf16(afr, ub, acc[1][nt], 0, 0, 0);
        }
    }

    // ---- epilogue: bias(+FiLM) -> LDS tile -> full-line NT stores ----
    const float* bias  = isNode ? (fb2 + f * D_) : eb2;
    const float* gamma = gbAll + b * 2 * D_;
    const float* beta  = gamma + D_;
    float* base = isNode ? (V + (((long)b * N_ + n0) * F_ + f) * D_)
                         : (E + ((long)b * NE_ + e0blk) * D_);
    const long stride  = isNode ? (long)F_ * D_ : (long)D_;   // floats
    const int rowsValid = isNode ? (N_ - n0) : 128;

    __syncthreads();   // all MFMA w2lds reads done -> outF may alias

    #pragma unroll
    for (int p = 0; p < 2; ++p) {
        #pragma unroll
        for (int ntl = 0; ntl < 4; ++ntl) {
            const int nt = p * 4 + ntl;
            const int d0 = nt * 16 + kg * 4;
            const f32x4 bs = *(const f32x4*)(bias + d0);
            f32x4 g, be;
            if (isNode) { g = *(const f32x4*)(gamma + d0); be = *(const f32x4*)(beta + d0); }
            #pragma unroll
            for (int mt = 0; mt < 2; ++mt) {
                const int m = wv * 32 + mt * 16 + lr;
                f32x4 v;
                #pragma unroll
                for (int r = 0; r < 4; ++r)
                    v[r] = isNode ? (acc[mt][nt][r] + bs[r]) * g[r] + be[r]
                                  : acc[mt][nt][r] + bs[r];
                *(f32x4*)(outF + m * 68 + ntl * 16 + kg * 4) = v;
            }
        }
        __syncthreads();
        #pragma unroll
        for (int j = 0; j < 8; ++j) {
            const int r = wv * 32 + j * 4 + (lane >> 4);
            const int c = (lane & 15) * 4;
            f32x4 v = *(const f32x4*)(outF + r * 68 + c);
            if (r < rowsValid)
                __builtin_nontemporal_store(v, (f32x4*)(base + (long)r * stride + p * 64 + c));
        }
        __syncthreads();
    }
}

// ---------------------------------------------------------------------------
extern "C" void kernel_launch(void* const* d_in, const int* in_sizes, int n_in,
                              void* d_out, int out_size, void* d_ws, size_t ws_size,
                              hipStream_t stream)
{
    (void)in_sizes; (void)n_in; (void)out_size; (void)ws_size;

    const float* node_pos  = (const float*)d_in[0];
    const float* state_in  = (const float*)d_in[1];
    const float* time_i    = (const float*)d_in[2];
    const float* conditions= (const float*)d_in[3];
    const float* spatial   = (const float*)d_in[4];
    const int*   edges     = (const int*)d_in[5];
    const float* fields_w1 = (const float*)d_in[6];
    const float* fields_b1 = (const float*)d_in[7];
    const float* fields_w2 = (const float*)d_in[8];
    const float* fields_b2 = (const float*)d_in[9];
    const float* tw1 = (const float*)d_in[10];
    const float* tb1 = (const float*)d_in[11];
    const float* tw2 = (const float*)d_in[12];
    const float* tb2 = (const float*)d_in[13];
    const float* cw1 = (const float*)d_in[14];
    const float* cb1 = (const float*)d_in[15];
    const float* cw2 = (const float*)d_in[16];
    const float* cb2 = (const float*)d_in[17];
    const float* sw1 = (const float*)d_in[18];
    const float* sb1 = (const float*)d_in[19];
    const float* sw2 = (const float*)d_in[20];
    const float* sb2 = (const float*)d_in[21];
    const float* fu_w1 = (const float*)d_in[22];
    const float* fu_b1 = (const float*)d_in[23];
    const float* fu_w2 = (const float*)d_in[24];
    const float* fu_b2 = (const float*)d_in[25];
    const float* fe_w1 = (const float*)d_in[26];
    const float* fe_b1 = (const float*)d_in[27];
    const float* fe_w2 = (const float*)d_in[28];
    const float* fe_b2 = (const float*)d_in[29];

    char*  ws = (char*)d_ws;
    float* V  = (float*)d_out;                // [B][N][F][D] f32
    float* E  = V + (long)B_ * N_ * F_ * D_;  // [B][NE][D] f32

    prep_kernel<<<dim3(6), dim3(256), 0, stream>>>(
        time_i, conditions, spatial,
        tw1, tb1, tw2, tb2, cw1, cb1, cw2, cb2, sw1, sb1, sw2, sb2,
        fu_w1, fu_b1, fu_w2, fu_b2,
        fields_w1, fields_b1, fields_w2,
        fe_w1, fe_b1, fe_w2,
        edges, ws);

    fused_kernel<<<dim3(TOTAL_NB), dim3(256), 0, stream>>>(
        node_pos, state_in, edges, fields_b2, fe_b2, ws, V, E);
}